// Round 3
// baseline (2111.251 us; speedup 1.0000x reference)
//
#include <hip/hip_runtime.h>
#include <cmath>

// Multi-scale residual VQ, round 3.
// Large scales (pn>=8): inline area-down + grouped code scan + packed-u64
// atomicMin (min d, tie -> min v; order-independent => deterministic).
// Small scales (pn<=6): down_k + block of 16 points x 16 code-lanes, local reduce.
// fuse_k: decode idx -> gather+separable bicubic (LDS) -> padded 3x3 conv Phi
// -> f_hat += hf, f_rest -= hf; also resets next scale's key buffer.

#define BB 64
#define CC 32
#define HH 16
#define VV 4096
#define NTOT (BB*CC*HH*HH)   // 524288
#define NKEY (BB*HH*HH)      // 16384 max points

__device__ __forceinline__ double cubicw(double x) {
    x = fabs(x);
    const double a = -0.75;
    if (x <= 1.0) return ((a + 2.0) * x - (a + 3.0)) * x * x + 1.0;
    if (x < 2.0)  return (((a * x - 5.0 * a) * x + 8.0 * a) * x - 4.0 * a);
    return 0.0;
}

__device__ __forceinline__ unsigned int ordf(float d) {
    unsigned int b = __float_as_uint(d);
    return (b & 0x80000000u) ? ~b : (b | 0x80000000u);
}

__global__ void init_k(const float* __restrict__ f, const float* __restrict__ E,
                       float* __restrict__ f_rest, float* __restrict__ f_hat,
                       float* __restrict__ e2, unsigned long long* __restrict__ k0,
                       unsigned long long* __restrict__ k1) {
    int i = blockIdx.x * 256 + threadIdx.x;
    if (i < NTOT) { f_rest[i] = f[i]; f_hat[i] = 0.f; }
    if (i < VV) {
        float s = 0.f;
        #pragma unroll
        for (int c = 0; c < CC; ++c) { float e = E[i * CC + c]; s += e * e; }
        e2[i] = s;
    }
    if (i < NKEY) { k0[i] = ~0ull; k1[i] = ~0ull; }
}

// z[m*C+c] = area-downsample of f_rest (pn<=6 path)
__global__ void down_k(const float* __restrict__ f_rest, float* __restrict__ z, int pn) {
    int id = blockIdx.x * 256 + threadIdx.x;
    int total = BB * pn * pn * CC;
    if (id >= total) return;
    int c = id & (CC - 1);
    int r = id >> 5;
    int q = r % pn; r /= pn;
    int p = r % pn; int b = r / pn;
    int sp = (p * HH) / pn, ep = ((p + 1) * HH + pn - 1) / pn;
    int sq = (q * HH) / pn, eq = ((q + 1) * HH + pn - 1) / pn;
    float wgt = 1.0f / ((float)(ep - sp) * (float)(eq - sq));
    const float* src = f_rest + ((size_t)(b * CC + c)) * HH * HH;
    float s = 0.f;
    for (int h = sp; h < ep; ++h)
        for (int w = sq; w < eq; ++w)
            s += src[h * HH + w];
    z[id] = s * wgt;
}

// Small scales: block = 16 points x 16 code-lanes; each thread scans 256 codes.
__global__ __launch_bounds__(256, 4) void argsmall_k(const float* __restrict__ z,
        const float* __restrict__ E, const float* __restrict__ e2,
        unsigned long long* __restrict__ key, int M) {
    int t = threadIdx.x;
    int vj = t & 15, mi = t >> 4;
    int m = blockIdx.x * 16 + mi;           // M divisible by 16 for all pn<=6
    float zr[CC]; float z2 = 0.f;
    const float4* zp = (const float4*)(z + (size_t)m * CC);
    #pragma unroll
    for (int c4 = 0; c4 < 8; ++c4) {
        float4 v = zp[c4];
        zr[c4*4+0] = v.x; zr[c4*4+1] = v.y; zr[c4*4+2] = v.z; zr[c4*4+3] = v.w;
        z2 += v.x*v.x + v.y*v.y + v.z*v.z + v.w*v.w;
    }
    const float* e = E + (size_t)vj * 256 * CC;
    float best = 3.4e38f; int bv = vj * 256;
    for (int v = vj * 256; v < vj * 256 + 256; v += 2, e += 2 * CC) {
        float a0 = 0.f, a1 = 0.f, b0 = 0.f, b1 = 0.f;
        #pragma unroll
        for (int c = 0; c < CC; c += 2) {
            a0 = fmaf(zr[c],   e[c],      a0);
            a1 = fmaf(zr[c+1], e[c+1],    a1);
            b0 = fmaf(zr[c],   e[CC+c],   b0);
            b1 = fmaf(zr[c+1], e[CC+c+1], b1);
        }
        float dA = fmaf(-2.f, a0 + a1, z2 + e2[v]);
        float dB = fmaf(-2.f, b0 + b1, z2 + e2[v+1]);
        if (dA < best) { best = dA; bv = v; }
        if (dB < best) { best = dB; bv = v + 1; }
    }
    __shared__ float sd[16][17];
    __shared__ int   sv[16][17];
    sd[mi][vj] = best; sv[mi][vj] = bv;
    __syncthreads();
    if (t < 16) {
        int mm = blockIdx.x * 16 + t;
        float bb = sd[t][0]; int vv = sv[t][0];
        #pragma unroll
        for (int j = 1; j < 16; ++j) {
            float d = sd[t][j];
            if (d < bb) { bb = d; vv = sv[t][j]; }   // vj ascending => first-min
        }
        key[mm] = (unsigned long long)(unsigned int)vv;
    }
}

// Large scales: thread-per-point, inline area-down, group g scans gsz codes,
// one packed atomicMin per (point, group).
__global__ __launch_bounds__(256, 4) void argbig_k(const float* __restrict__ f_rest,
        const float* __restrict__ E, const float* __restrict__ e2,
        unsigned long long* __restrict__ key, int pn, int M, int gsz) {
    int m0 = blockIdx.x * 256 + threadIdx.x;
    int g = blockIdx.y;
    bool act = (m0 < M);
    int m = act ? m0 : M - 1;
    int q = m % pn; int r = m / pn;
    int p = r % pn; int b = r / pn;
    int sp = (p * HH) / pn, ep = ((p + 1) * HH + pn - 1) / pn;
    int sq = (q * HH) / pn, eq = ((q + 1) * HH + pn - 1) / pn;
    float wgt = 1.0f / ((float)(ep - sp) * (float)(eq - sq));
    const float* src = f_rest + (size_t)b * (CC * HH * HH);
    float zr[CC]; float z2 = 0.f;
    #pragma unroll
    for (int c = 0; c < CC; ++c) {
        float s = 0.f;
        for (int h = sp; h < ep; ++h)
            for (int w = sq; w < eq; ++w)
                s += src[c * (HH * HH) + h * HH + w];
        zr[c] = s * wgt;
        z2 += zr[c] * zr[c];
    }
    int v0 = g * gsz;
    const float* e = E + (size_t)v0 * CC;
    float best = 3.4e38f; int bv = v0;
    for (int v = v0; v < v0 + gsz; v += 2, e += 2 * CC) {
        float a0 = 0.f, a1 = 0.f, b0 = 0.f, b1 = 0.f;
        #pragma unroll
        for (int c = 0; c < CC; c += 2) {
            a0 = fmaf(zr[c],   e[c],      a0);
            a1 = fmaf(zr[c+1], e[c+1],    a1);
            b0 = fmaf(zr[c],   e[CC+c],   b0);
            b1 = fmaf(zr[c+1], e[CC+c+1], b1);
        }
        float dA = fmaf(-2.f, a0 + a1, z2 + e2[v]);
        float dB = fmaf(-2.f, b0 + b1, z2 + e2[v+1]);
        if (dA < best) { best = dA; bv = v; }
        if (dB < best) { best = dB; bv = v + 1; }
    }
    if (act) {
        unsigned long long k = ((unsigned long long)ordf(best) << 32) |
                               (unsigned long long)(unsigned int)bv;
        atomicMin(&key[m], k);
    }
}

// Fused: decode idx -> gather + separable bicubic in LDS (vertically padded)
// -> 3x3 conv Phi -> f_hat += hf, f_rest -= hf. Also resets next key buffer.
__global__ __launch_bounds__(256) void fuse_k(const unsigned long long* __restrict__ key,
                      unsigned long long* __restrict__ key_other,
                      const float* __restrict__ E,
                      const float* __restrict__ pw, const float* __restrict__ pb,
                      float* __restrict__ f_hat, float* __restrict__ f_rest,
                      int pn, int kphi) {
    __shared__ float s_buf[CC * 18 * 20];   // phase A: tmp[c][16][pn]; then hup[c][18][20] padded
    __shared__ float s_pw[8 * CC * 9];
    __shared__ int   s_idx[256];
    __shared__ float s_w[HH][4];
    __shared__ int   s_j[HH][4];
    const int t   = threadIdx.x;
    const int cog = blockIdx.x;   // 0..3
    const int b   = blockIdx.y;   // 0..63

    // reset the other key buffer for the next scale's atomicMin
    {
        int bi = blockIdx.y * 4 + blockIdx.x;
        if (t < 64) key_other[bi * 64 + t] = ~0ull;
    }

    // ---- phase 0 ----
    if (t < pn * pn) s_idx[t] = (int)(unsigned int)key[b * pn * pn + t];
    if (t < HH) {
        double src = (t + 0.5) * (double)pn / 16.0 - 0.5;
        double fi = floor(src); int i0 = (int)fi; double tt = src - fi;
        #pragma unroll
        for (int k = 0; k < 4; ++k) {
            int j = i0 - 1 + k; j = j < 0 ? 0 : (j > pn - 1 ? pn - 1 : j);
            s_j[t][k] = j;
            s_w[t][k] = (float)cubicw((double)(k - 1) - tt);
        }
    }
    {
        const float* src = pw + ((size_t)(kphi * CC + cog * 8)) * CC * 9;
        for (int i = t; i < 8 * CC * 9; i += 256) s_pw[i] = src[i];
    }
    __syncthreads();

    // ---- phase A: vertical bicubic + gather: tmp[c][h][q] ----
    if (t < HH * pn) {
        int h = t / pn, q = t % pn;
        float acc[CC];
        #pragma unroll
        for (int c = 0; c < CC; ++c) acc[c] = 0.f;
        #pragma unroll
        for (int k = 0; k < 4; ++k) {
            float wv = s_w[h][k];
            int row = s_idx[s_j[h][k] * pn + q];
            const float4* er = (const float4*)(E + (size_t)row * CC);
            #pragma unroll
            for (int c4 = 0; c4 < CC / 4; ++c4) {
                float4 e4 = er[c4];
                acc[c4*4+0] = fmaf(wv, e4.x, acc[c4*4+0]);
                acc[c4*4+1] = fmaf(wv, e4.y, acc[c4*4+1]);
                acc[c4*4+2] = fmaf(wv, e4.z, acc[c4*4+2]);
                acc[c4*4+3] = fmaf(wv, e4.w, acc[c4*4+3]);
            }
        }
        #pragma unroll
        for (int c = 0; c < CC; ++c) s_buf[(c * HH + h) * pn + q] = acc[c];
    }
    __syncthreads();

    // ---- phase B: horizontal bicubic -> padded hup[c][18][20] (data at [1..16][1..16]) ----
    {
        int h = t >> 4, w = t & 15;
        float acc[CC];
        #pragma unroll
        for (int c = 0; c < CC; ++c) acc[c] = 0.f;
        #pragma unroll
        for (int k = 0; k < 4; ++k) {
            float wh = s_w[w][k];
            int j = s_j[w][k];
            #pragma unroll
            for (int c = 0; c < CC; ++c)
                acc[c] = fmaf(wh, s_buf[(c * HH + h) * pn + j], acc[c]);
        }
        __syncthreads();   // all tmp reads done before aliased writes
        #pragma unroll
        for (int c = 0; c < CC; ++c) s_buf[(c * 18 + h + 1) * 20 + w + 1] = acc[c];
        if (w == 0) {
            #pragma unroll
            for (int c = 0; c < CC; ++c) s_buf[(c * 18 + h + 1) * 20] = 0.f;
        }
        if (w >= 13) {   // cols 17,18,19
            #pragma unroll
            for (int c = 0; c < CC; ++c) s_buf[(c * 18 + h + 1) * 20 + w + 4] = 0.f;
        }
        if (h == 0) {
            #pragma unroll
            for (int c = 0; c < CC; ++c) {
                s_buf[(c * 18) * 20 + w] = 0.f;
                if (w < 4) s_buf[(c * 18) * 20 + 16 + w] = 0.f;
            }
        }
        if (h == 15) {
            #pragma unroll
            for (int c = 0; c < CC; ++c) {
                s_buf[(c * 18 + 17) * 20 + w] = 0.f;
                if (w < 4) s_buf[(c * 18 + 17) * 20 + 16 + w] = 0.f;
            }
        }
    }
    __syncthreads();

    // ---- conv 3x3 (no boundary branches thanks to padding) ----
    int col = t >> 5;                 // 0..7
    int co  = cog * 8 + col;
    int s   = t & 31;
    int h   = s >> 1;
    int w0  = (s & 1) * 8;
    float acc[8];
    float bias = pb[kphi * CC + co];
    #pragma unroll
    for (int o = 0; o < 8; ++o) acc[o] = bias;
    for (int ci = 0; ci < CC; ++ci) {
        const float* wrow = &s_pw[(col * CC + ci) * 9];
        #pragma unroll
        for (int kh = 0; kh < 3; ++kh) {
            const float4* xr = (const float4*)&s_buf[(ci * 18 + h + kh) * 20 + w0];
            float4 a0 = xr[0], a1 = xr[1], a2 = xr[2];
            float xf[12] = {a0.x, a0.y, a0.z, a0.w, a1.x, a1.y, a1.z, a1.w,
                            a2.x, a2.y, a2.z, a2.w};
            float k0 = wrow[kh*3+0], k1 = wrow[kh*3+1], k2 = wrow[kh*3+2];
            #pragma unroll
            for (int o = 0; o < 8; ++o)
                acc[o] += xf[o] * k0 + xf[o+1] * k1 + xf[o+2] * k2;
        }
    }
    // ---- epilogue ----
    size_t base = ((size_t)(b * CC + co) * HH + h) * HH + w0;
    float hf[8];
    #pragma unroll
    for (int o = 0; o < 8; ++o) {
        float hv = s_buf[(co * 18 + h + 1) * 20 + w0 + o + 1];
        hf[o] = 0.5f * hv + 0.5f * acc[o];
    }
    float4* fh = (float4*)(f_hat + base);
    float4* fr = (float4*)(f_rest + base);
    float4 v0 = fh[0], v1 = fh[1];
    v0.x += hf[0]; v0.y += hf[1]; v0.z += hf[2]; v0.w += hf[3];
    v1.x += hf[4]; v1.y += hf[5]; v1.z += hf[6]; v1.w += hf[7];
    fh[0] = v0; fh[1] = v1;
    float4 r0 = fr[0], r1 = fr[1];
    r0.x -= hf[0]; r0.y -= hf[1]; r0.z -= hf[2]; r0.w -= hf[3];
    r1.x -= hf[4]; r1.y -= hf[5]; r1.z -= hf[6]; r1.w -= hf[7];
    fr[0] = r0; fr[1] = r1;
}

extern "C" void kernel_launch(void* const* d_in, const int* in_sizes, int n_in,
                              void* d_out, int out_size, void* d_ws, size_t ws_size,
                              hipStream_t stream) {
    const float* f  = (const float*)d_in[0];
    const float* E  = (const float*)d_in[1];
    const float* pw = (const float*)d_in[2];
    const float* pb = (const float*)d_in[3];
    float* out = (float*)d_out;

    float* wsf    = (float*)d_ws;
    float* f_rest = wsf;
    float* z      = wsf + (size_t)NTOT;
    float* e2     = wsf + (size_t)2 * NTOT;
    unsigned long long* keys = (unsigned long long*)(e2 + VV);  // 8B-aligned (even float offset)

    // numpy _phi_select, bit-exact in IEEE double (ties at si=2,7)
    int phik[10];
    {
        double start = 1.0 / 3.0 / 4.0;
        double stop  = 1.0 - 1.0 / 3.0 / 4.0;
        double step  = (stop - start) / 3.0;
        double ticks[4];
        for (int i = 0; i < 4; ++i) ticks[i] = (double)i * step + start;
        ticks[3] = stop;
        for (int si = 0; si < 10; ++si) {
            double s = (double)si / 9.0;
            int bk = 0; double bd = fabs(ticks[0] - s);
            for (int tq = 1; tq < 4; ++tq) {
                double d2 = fabs(ticks[tq] - s);
                if (d2 < bd) { bd = d2; bk = tq; }
            }
            phik[si] = bk;
        }
    }

    static const int pns[10] = {1, 2, 3, 4, 5, 6, 8, 10, 13, 16};

    init_k<<<(NTOT + 255) / 256, 256, 0, stream>>>(f, E, f_rest, out, e2,
                                                   keys, keys + NKEY);

    for (int si = 0; si < 10; ++si) {
        int pn = pns[si];
        int M = BB * pn * pn;
        unsigned long long* keyA = keys + (size_t)(si & 1) * NKEY;
        unsigned long long* keyB = keys + (size_t)((si + 1) & 1) * NKEY;
        if (pn <= 6) {
            int n1 = M * CC;
            down_k<<<(n1 + 255) / 256, 256, 0, stream>>>(f_rest, z, pn);
            argsmall_k<<<M / 16, 256, 0, stream>>>(z, E, e2, keyA, M);
        } else {
            int grp = (pn >= 13) ? 32 : 64;
            int gsz = VV / grp;
            dim3 ag((M + 255) / 256, grp);
            argbig_k<<<ag, 256, 0, stream>>>(f_rest, E, e2, keyA, pn, M, gsz);
        }
        fuse_k<<<dim3(4, BB), 256, 0, stream>>>(keyA, keyB, E, pw, pb,
                                                out, f_rest, pn, phik[si]);
    }
}

// Round 5
// 1030.102 us; speedup vs baseline: 2.0496x; 2.0496x over previous
//
#include <hip/hip_runtime.h>
#include <cmath>

// Multi-scale residual VQ, round 5: fully deterministic two-stage argmin
// (plain stores + explicit reduce in fuse_k; NO atomics, NO cross-kernel
// state, NO 64-bit shuffles). Topology proven by R2's passing run; grids
// sized for occupancy per R4's analysis.

#define BB 64
#define CC 32
#define HH 16
#define VV 4096
#define NTOT (BB*CC*HH*HH)   // 524288

__device__ __forceinline__ double cubicw(double x) {
    x = fabs(x);
    const double a = -0.75;
    if (x <= 1.0) return ((a + 2.0) * x - (a + 3.0)) * x * x + 1.0;
    if (x < 2.0)  return (((a * x - 5.0 * a) * x + 8.0 * a) * x - 4.0 * a);
    return 0.0;
}

// monotone float->uint map: d1<d2 (finite) => ordf(d1)<ordf(d2)
__device__ __forceinline__ unsigned int ordf(float d) {
    unsigned int b = __float_as_uint(d);
    return (b & 0x80000000u) ? ~b : (b | 0x80000000u);
}

__global__ void init_k(const float* __restrict__ f, const float* __restrict__ E,
                       float* __restrict__ f_rest, float* __restrict__ f_hat,
                       float* __restrict__ e2) {
    int i = blockIdx.x * 256 + threadIdx.x;
    if (i < NTOT) { f_rest[i] = f[i]; f_hat[i] = 0.f; }
    if (i < VV) {
        float s = 0.f;
        #pragma unroll
        for (int c = 0; c < CC; ++c) { float e = E[i * CC + c]; s += e * e; }
        e2[i] = s;
    }
}

// Small scales (pn<=6): grid (M, grp). Inline area-downsample into LDS,
// each thread scans cpt codes, deterministic LDS tree reduce, plain store.
__global__ __launch_bounds__(256, 4) void argsmall_k(const float* __restrict__ f_rest,
        const float* __restrict__ E, const float* __restrict__ e2,
        unsigned long long* __restrict__ bestk, int pn, int M, int cpt) {
    __shared__ float s_z[CC];
    __shared__ unsigned long long s_red[256];
    const int t = threadIdx.x;
    const int m = blockIdx.x;
    const int g = blockIdx.y;
    if (t < CC) {
        int q = m % pn; int r = m / pn;
        int p = r % pn; int b = r / pn;
        int sp = (p * HH) / pn, ep = ((p + 1) * HH + pn - 1) / pn;
        int sq = (q * HH) / pn, eq = ((q + 1) * HH + pn - 1) / pn;
        float wgt = 1.0f / ((float)(ep - sp) * (float)(eq - sq));
        const float* src = f_rest + ((size_t)(b * CC + t)) * (HH * HH);
        float s = 0.f;
        for (int h = sp; h < ep; ++h)
            for (int w = sq; w < eq; ++w)
                s += src[h * HH + w];
        s_z[t] = s * wgt;
    }
    __syncthreads();
    float zr[CC]; float z2 = 0.f;
    #pragma unroll
    for (int c = 0; c < CC; ++c) { zr[c] = s_z[c]; z2 += zr[c] * zr[c]; }
    int v0 = g * (cpt << 8) + t * cpt;
    const float* e = E + (size_t)v0 * CC;
    float best = 3.4e38f; int bv = v0;
    for (int i = 0; i < cpt; ++i, e += CC) {
        float a0 = 0.f, a1 = 0.f;
        #pragma unroll
        for (int c = 0; c < CC; c += 2) {
            a0 = fmaf(zr[c],     e[c],     a0);
            a1 = fmaf(zr[c + 1], e[c + 1], a1);
        }
        float d = fmaf(-2.f, a0 + a1, z2 + e2[v0 + i]);
        if (d < best) { best = d; bv = v0 + i; }   // ascending v => first-min
    }
    s_red[t] = ((unsigned long long)ordf(best) << 32) |
               (unsigned long long)(unsigned int)bv;
    __syncthreads();
    #pragma unroll
    for (int s = 128; s > 0; s >>= 1) {
        if (t < s) {
            unsigned long long o = s_red[t + s];
            if (o < s_red[t]) s_red[t] = o;
        }
        __syncthreads();
    }
    if (t == 0) bestk[(size_t)g * M + m] = s_red[0];
}

// Large scales (pn>=8): thread-per-point, inline area-down, group g scans gsz
// codes, plain store of packed (d,v) to bestk[g*M+m].
__global__ __launch_bounds__(256, 4) void argbig_k(const float* __restrict__ f_rest,
        const float* __restrict__ E, const float* __restrict__ e2,
        unsigned long long* __restrict__ bestk, int pn, int M, int gsz) {
    int m0 = blockIdx.x * 256 + threadIdx.x;
    int g = blockIdx.y;
    bool act = (m0 < M);
    int m = act ? m0 : M - 1;
    int q = m % pn; int r = m / pn;
    int p = r % pn; int b = r / pn;
    int sp = (p * HH) / pn, ep = ((p + 1) * HH + pn - 1) / pn;
    int sq = (q * HH) / pn, eq = ((q + 1) * HH + pn - 1) / pn;
    float wgt = 1.0f / ((float)(ep - sp) * (float)(eq - sq));
    const float* src = f_rest + (size_t)b * (CC * HH * HH);
    float zr[CC]; float z2 = 0.f;
    #pragma unroll
    for (int c = 0; c < CC; ++c) {
        float s = 0.f;
        for (int h = sp; h < ep; ++h)
            for (int w = sq; w < eq; ++w)
                s += src[c * (HH * HH) + h * HH + w];
        zr[c] = s * wgt;
        z2 += zr[c] * zr[c];
    }
    int v0 = g * gsz;
    const float* e = E + (size_t)v0 * CC;
    float best = 3.4e38f; int bv = v0;
    for (int v = v0; v < v0 + gsz; v += 2, e += 2 * CC) {
        float a0 = 0.f, a1 = 0.f, b0 = 0.f, b1 = 0.f;
        #pragma unroll
        for (int c = 0; c < CC; c += 2) {
            a0 = fmaf(zr[c],   e[c],      a0);
            a1 = fmaf(zr[c+1], e[c+1],    a1);
            b0 = fmaf(zr[c],   e[CC+c],   b0);
            b1 = fmaf(zr[c+1], e[CC+c+1], b1);
        }
        float dA = fmaf(-2.f, a0 + a1, z2 + e2[v]);
        float dB = fmaf(-2.f, b0 + b1, z2 + e2[v+1]);
        if (dA < best) { best = dA; bv = v; }
        if (dB < best) { best = dB; bv = v + 1; }
    }
    if (act)
        bestk[(size_t)g * M + m] = ((unsigned long long)ordf(best) << 32) |
                                   (unsigned long long)(unsigned int)bv;
}

// Fused: group-reduce packed keys -> gather + separable bicubic in LDS
// (padded) -> 3x3 conv Phi -> f_hat += hf, f_rest -= hf.
__global__ __launch_bounds__(256) void fuse_k(const unsigned long long* __restrict__ bestk,
                      const float* __restrict__ E,
                      const float* __restrict__ pw, const float* __restrict__ pb,
                      float* __restrict__ f_hat, float* __restrict__ f_rest,
                      int pn, int grp, int kphi) {
    __shared__ float s_buf[CC * 18 * 20];   // phase A: tmp[c][16][pn]; then hup[c][18][20]
    __shared__ float s_pw[8 * CC * 9];
    __shared__ int   s_idx[256];
    __shared__ float s_w[HH][4];
    __shared__ int   s_j[HH][4];
    const int t   = threadIdx.x;
    const int cog = blockIdx.x;   // 0..3
    const int b   = blockIdx.y;   // 0..63
    const int M   = BB * pn * pn;

    // ---- phase 0: reduce over groups (packed u64: min d, tie -> min v) ----
    if (t < pn * pn) {
        int m = b * pn * pn + t;
        unsigned long long bk = bestk[m];
        for (int g = 1; g < grp; ++g) {
            unsigned long long o = bestk[(size_t)g * M + m];
            if (o < bk) bk = o;
        }
        s_idx[t] = (int)(unsigned int)(bk & 0xffffffffull);
    }
    if (t < HH) {
        double src = (t + 0.5) * (double)pn / 16.0 - 0.5;
        double fi = floor(src); int i0 = (int)fi; double tt = src - fi;
        #pragma unroll
        for (int k = 0; k < 4; ++k) {
            int j = i0 - 1 + k; j = j < 0 ? 0 : (j > pn - 1 ? pn - 1 : j);
            s_j[t][k] = j;
            s_w[t][k] = (float)cubicw((double)(k - 1) - tt);
        }
    }
    {
        const float* src = pw + ((size_t)(kphi * CC + cog * 8)) * CC * 9;
        for (int i = t; i < 8 * CC * 9; i += 256) s_pw[i] = src[i];
    }
    __syncthreads();

    // ---- phase A: vertical bicubic + gather: tmp[c][h][q] ----
    if (t < HH * pn) {
        int h = t / pn, q = t % pn;
        float acc[CC];
        #pragma unroll
        for (int c = 0; c < CC; ++c) acc[c] = 0.f;
        #pragma unroll
        for (int k = 0; k < 4; ++k) {
            float wv = s_w[h][k];
            int row = s_idx[s_j[h][k] * pn + q];
            const float4* er = (const float4*)(E + (size_t)row * CC);
            #pragma unroll
            for (int c4 = 0; c4 < CC / 4; ++c4) {
                float4 e4 = er[c4];
                acc[c4*4+0] = fmaf(wv, e4.x, acc[c4*4+0]);
                acc[c4*4+1] = fmaf(wv, e4.y, acc[c4*4+1]);
                acc[c4*4+2] = fmaf(wv, e4.z, acc[c4*4+2]);
                acc[c4*4+3] = fmaf(wv, e4.w, acc[c4*4+3]);
            }
        }
        #pragma unroll
        for (int c = 0; c < CC; ++c) s_buf[(c * HH + h) * pn + q] = acc[c];
    }
    __syncthreads();

    // ---- phase B: horizontal bicubic -> padded hup[c][18][20] (data [1..16][1..16]) ----
    {
        int h = t >> 4, w = t & 15;
        float acc[CC];
        #pragma unroll
        for (int c = 0; c < CC; ++c) acc[c] = 0.f;
        #pragma unroll
        for (int k = 0; k < 4; ++k) {
            float wh = s_w[w][k];
            int j = s_j[w][k];
            #pragma unroll
            for (int c = 0; c < CC; ++c)
                acc[c] = fmaf(wh, s_buf[(c * HH + h) * pn + j], acc[c]);
        }
        __syncthreads();   // all tmp reads done before aliased writes
        #pragma unroll
        for (int c = 0; c < CC; ++c) s_buf[(c * 18 + h + 1) * 20 + w + 1] = acc[c];
        if (w == 0) {
            #pragma unroll
            for (int c = 0; c < CC; ++c) s_buf[(c * 18 + h + 1) * 20] = 0.f;
        }
        if (w >= 13) {   // cols 17,18,19
            #pragma unroll
            for (int c = 0; c < CC; ++c) s_buf[(c * 18 + h + 1) * 20 + w + 4] = 0.f;
        }
        if (h == 0) {
            #pragma unroll
            for (int c = 0; c < CC; ++c) {
                s_buf[(c * 18) * 20 + w] = 0.f;
                if (w < 4) s_buf[(c * 18) * 20 + 16 + w] = 0.f;
            }
        }
        if (h == 15) {
            #pragma unroll
            for (int c = 0; c < CC; ++c) {
                s_buf[(c * 18 + 17) * 20 + w] = 0.f;
                if (w < 4) s_buf[(c * 18 + 17) * 20 + 16 + w] = 0.f;
            }
        }
    }
    __syncthreads();

    // ---- conv 3x3 (padded, branch-free) ----
    int col = t >> 5;                 // 0..7
    int co  = cog * 8 + col;
    int s   = t & 31;
    int h   = s >> 1;
    int w0  = (s & 1) * 8;
    float acc[8];
    float bias = pb[kphi * CC + co];
    #pragma unroll
    for (int o = 0; o < 8; ++o) acc[o] = bias;
    for (int ci = 0; ci < CC; ++ci) {
        const float* wrow = &s_pw[(col * CC + ci) * 9];
        #pragma unroll
        for (int kh = 0; kh < 3; ++kh) {
            const float4* xr = (const float4*)&s_buf[(ci * 18 + h + kh) * 20 + w0];
            float4 a0 = xr[0], a1 = xr[1], a2 = xr[2];
            float xf[12] = {a0.x, a0.y, a0.z, a0.w, a1.x, a1.y, a1.z, a1.w,
                            a2.x, a2.y, a2.z, a2.w};
            float k0 = wrow[kh*3+0], k1 = wrow[kh*3+1], k2 = wrow[kh*3+2];
            #pragma unroll
            for (int o = 0; o < 8; ++o)
                acc[o] += xf[o] * k0 + xf[o+1] * k1 + xf[o+2] * k2;
        }
    }
    // ---- epilogue ----
    size_t base = ((size_t)(b * CC + co) * HH + h) * HH + w0;
    float hf[8];
    #pragma unroll
    for (int o = 0; o < 8; ++o) {
        float hv = s_buf[(co * 18 + h + 1) * 20 + w0 + o + 1];
        hf[o] = 0.5f * hv + 0.5f * acc[o];
    }
    float4* fh = (float4*)(f_hat + base);
    float4* fr = (float4*)(f_rest + base);
    float4 v0 = fh[0], v1 = fh[1];
    v0.x += hf[0]; v0.y += hf[1]; v0.z += hf[2]; v0.w += hf[3];
    v1.x += hf[4]; v1.y += hf[5]; v1.z += hf[6]; v1.w += hf[7];
    fh[0] = v0; fh[1] = v1;
    float4 r0 = fr[0], r1 = fr[1];
    r0.x -= hf[0]; r0.y -= hf[1]; r0.z -= hf[2]; r0.w -= hf[3];
    r1.x -= hf[4]; r1.y -= hf[5]; r1.z -= hf[6]; r1.w -= hf[7];
    fr[0] = r0; fr[1] = r1;
}

extern "C" void kernel_launch(void* const* d_in, const int* in_sizes, int n_in,
                              void* d_out, int out_size, void* d_ws, size_t ws_size,
                              hipStream_t stream) {
    const float* f  = (const float*)d_in[0];
    const float* E  = (const float*)d_in[1];
    const float* pw = (const float*)d_in[2];
    const float* pb = (const float*)d_in[3];
    float* out = (float*)d_out;

    float* wsf    = (float*)d_ws;
    float* f_rest = wsf;
    float* e2     = wsf + (size_t)NTOT;
    unsigned long long* bestk = (unsigned long long*)(e2 + VV);  // <=262144 u64 (2MB)

    // numpy _phi_select, bit-exact in IEEE double (ties at si=2,7)
    int phik[10];
    {
        double start = 1.0 / 3.0 / 4.0;
        double stop  = 1.0 - 1.0 / 3.0 / 4.0;
        double step  = (stop - start) / 3.0;
        double ticks[4];
        for (int i = 0; i < 4; ++i) ticks[i] = (double)i * step + start;
        ticks[3] = stop;
        for (int si = 0; si < 10; ++si) {
            double s = (double)si / 9.0;
            int bk = 0; double bd = fabs(ticks[0] - s);
            for (int tq = 1; tq < 4; ++tq) {
                double d2 = fabs(ticks[tq] - s);
                if (d2 < bd) { bd = d2; bk = tq; }
            }
            phik[si] = bk;
        }
    }

    static const int pns[10]  = {1, 2, 3, 4, 5, 6, 8, 10, 13, 16};
    // groups: small scales get blocks = M*grp; big scales get (M/256)*grp blocks
    static const int grps[10] = {4, 2, 1, 1, 1, 1, 64, 32, 16, 16};

    init_k<<<(NTOT + 255) / 256, 256, 0, stream>>>(f, E, f_rest, out, e2);

    for (int si = 0; si < 10; ++si) {
        int pn = pns[si];
        int M = BB * pn * pn;
        int grp = grps[si];
        if (pn <= 6) {
            int cpt = VV / (grp * 256);
            argsmall_k<<<dim3(M, grp), 256, 0, stream>>>(f_rest, E, e2, bestk, pn, M, cpt);
        } else {
            int gsz = VV / grp;
            dim3 ag((M + 255) / 256, grp);
            argbig_k<<<ag, 256, 0, stream>>>(f_rest, E, e2, bestk, pn, M, gsz);
        }
        fuse_k<<<dim3(4, BB), 256, 0, stream>>>(bestk, E, pw, pb,
                                                out, f_rest, pn, grp, phik[si]);
    }
}

// Round 6
// 692.209 us; speedup vs baseline: 3.0500x; 1.4881x over previous
//
#include <hip/hip_runtime.h>
#include <cmath>

// Multi-scale residual VQ, round 6.
// R5 lesson: per-thread-private code ranges => per-lane scattered E loads
// (64 L2 requests per wave load) => request-throughput bound at 4% VALU.
// Fix: ALL code loops are wave-uniform so E rows go down the scalar path.
//   small (pn<=6): down_k -> argsmall_k: wave = 64 points (one/lane),
//                  wave-specific code range via readfirstlane.
//   big (pn>=8):   argbig_k unchanged (already wave-uniform).
// Stage-2: deterministic cooperative LDS tree reduce inside fuse_k. No atomics.

#define BB 64
#define CC 32
#define HH 16
#define VV 4096
#define NTOT (BB*CC*HH*HH)   // 524288

__device__ __forceinline__ double cubicw(double x) {
    x = fabs(x);
    const double a = -0.75;
    if (x <= 1.0) return ((a + 2.0) * x - (a + 3.0)) * x * x + 1.0;
    if (x < 2.0)  return (((a * x - 5.0 * a) * x + 8.0 * a) * x - 4.0 * a);
    return 0.0;
}

// monotone float->uint map: d1<d2 (finite) => ordf(d1)<ordf(d2)
__device__ __forceinline__ unsigned int ordf(float d) {
    unsigned int b = __float_as_uint(d);
    return (b & 0x80000000u) ? ~b : (b | 0x80000000u);
}

__global__ void init_k(const float* __restrict__ f, const float* __restrict__ E,
                       float* __restrict__ f_rest, float* __restrict__ f_hat,
                       float* __restrict__ e2) {
    int i = blockIdx.x * 256 + threadIdx.x;
    if (i < NTOT) { f_rest[i] = f[i]; f_hat[i] = 0.f; }
    if (i < VV) {
        float s = 0.f;
        #pragma unroll
        for (int c = 0; c < CC; ++c) { float e = E[i * CC + c]; s += e * e; }
        e2[i] = s;
    }
}

// Area-downsample to z[m*C+c] (small scales; computed ONCE per scale).
__global__ void down_k(const float* __restrict__ f_rest, float* __restrict__ z, int pn) {
    int id = blockIdx.x * 256 + threadIdx.x;
    int total = BB * pn * pn * CC;
    if (id >= total) return;
    int c = id & (CC - 1);
    int r = id >> 5;
    int q = r % pn; r /= pn;
    int p = r % pn; int b = r / pn;
    int sp = (p * HH) / pn, ep = ((p + 1) * HH + pn - 1) / pn;
    int sq = (q * HH) / pn, eq = ((q + 1) * HH + pn - 1) / pn;
    float wgt = 1.0f / ((float)(ep - sp) * (float)(eq - sq));
    const float* src = f_rest + ((size_t)(b * CC + c)) * HH * HH;
    float s = 0.f;
    for (int h = sp; h < ep; ++h)
        for (int w = sq; w < eq; ++w)
            s += src[h * HH + w];
    z[id] = s * wgt;
}

// Small scales: grid (pn*pn, grp); block = 4 waves; each wave = same 64 points
// (one per lane), wave-specific code range (wave-uniform => scalar E loads).
__global__ __launch_bounds__(256, 4) void argsmall_k(const float* __restrict__ z,
        const float* __restrict__ E, const float* __restrict__ e2,
        unsigned long long* __restrict__ bestk, int M, int gsz) {
    const int t = threadIdx.x;
    int m = blockIdx.x * 64 + (t & 63);
    int w = __builtin_amdgcn_readfirstlane(t >> 6);      // wave id, SGPR
    int wg = blockIdx.y * 4 + w;
    int v0 = wg * gsz;                                    // scalar
    float zr[CC]; float z2 = 0.f;
    const float4* zp = (const float4*)(z + (size_t)m * CC);
    #pragma unroll
    for (int c4 = 0; c4 < 8; ++c4) {
        float4 v = zp[c4];
        zr[c4*4+0] = v.x; zr[c4*4+1] = v.y; zr[c4*4+2] = v.z; zr[c4*4+3] = v.w;
        z2 += v.x*v.x + v.y*v.y + v.z*v.z + v.w*v.w;
    }
    const float* e = E + (size_t)v0 * CC;
    float best = 3.4e38f; int bv = v0;
    for (int v = v0; v < v0 + gsz; v += 2, e += 2 * CC) {
        float a0 = 0.f, a1 = 0.f, b0 = 0.f, b1 = 0.f;
        #pragma unroll
        for (int c = 0; c < CC; c += 2) {
            a0 = fmaf(zr[c],   e[c],      a0);
            a1 = fmaf(zr[c+1], e[c+1],    a1);
            b0 = fmaf(zr[c],   e[CC+c],   b0);
            b1 = fmaf(zr[c+1], e[CC+c+1], b1);
        }
        float dA = fmaf(-2.f, a0 + a1, z2 + e2[v]);
        float dB = fmaf(-2.f, b0 + b1, z2 + e2[v+1]);
        if (dA < best) { best = dA; bv = v; }
        if (dB < best) { best = dB; bv = v + 1; }
    }
    bestk[(size_t)wg * M + m] = ((unsigned long long)ordf(best) << 32) |
                                (unsigned long long)(unsigned int)bv;
}

// Large scales (pn>=8): thread-per-point, inline area-down, wave-uniform code
// loop (scalar E loads), plain store of packed (d,v) to bestk[g*M+m].
__global__ __launch_bounds__(256, 4) void argbig_k(const float* __restrict__ f_rest,
        const float* __restrict__ E, const float* __restrict__ e2,
        unsigned long long* __restrict__ bestk, int pn, int M, int gsz) {
    int m0 = blockIdx.x * 256 + threadIdx.x;
    int g = blockIdx.y;
    bool act = (m0 < M);
    int m = act ? m0 : M - 1;
    int q = m % pn; int r = m / pn;
    int p = r % pn; int b = r / pn;
    int sp = (p * HH) / pn, ep = ((p + 1) * HH + pn - 1) / pn;
    int sq = (q * HH) / pn, eq = ((q + 1) * HH + pn - 1) / pn;
    float wgt = 1.0f / ((float)(ep - sp) * (float)(eq - sq));
    const float* src = f_rest + (size_t)b * (CC * HH * HH);
    float zr[CC]; float z2 = 0.f;
    #pragma unroll
    for (int c = 0; c < CC; ++c) {
        float s = 0.f;
        for (int h = sp; h < ep; ++h)
            for (int w = sq; w < eq; ++w)
                s += src[c * (HH * HH) + h * HH + w];
        zr[c] = s * wgt;
        z2 += zr[c] * zr[c];
    }
    int v0 = g * gsz;
    const float* e = E + (size_t)v0 * CC;
    float best = 3.4e38f; int bv = v0;
    for (int v = v0; v < v0 + gsz; v += 2, e += 2 * CC) {
        float a0 = 0.f, a1 = 0.f, b0 = 0.f, b1 = 0.f;
        #pragma unroll
        for (int c = 0; c < CC; c += 2) {
            a0 = fmaf(zr[c],   e[c],      a0);
            a1 = fmaf(zr[c+1], e[c+1],    a1);
            b0 = fmaf(zr[c],   e[CC+c],   b0);
            b1 = fmaf(zr[c+1], e[CC+c+1], b1);
        }
        float dA = fmaf(-2.f, a0 + a1, z2 + e2[v]);
        float dB = fmaf(-2.f, b0 + b1, z2 + e2[v+1]);
        if (dA < best) { best = dA; bv = v; }
        if (dB < best) { best = dB; bv = v + 1; }
    }
    if (act)
        bestk[(size_t)g * M + m] = ((unsigned long long)ordf(best) << 32) |
                                   (unsigned long long)(unsigned int)bv;
}

// Fused: cooperative group-reduce of packed keys -> gather + separable bicubic
// in LDS (padded) -> 3x3 conv Phi -> f_hat += hf, f_rest -= hf.
__global__ __launch_bounds__(256) void fuse_k(const unsigned long long* __restrict__ bestk,
                      const float* __restrict__ E,
                      const float* __restrict__ pw, const float* __restrict__ pb,
                      float* __restrict__ f_hat, float* __restrict__ f_rest,
                      int pn, int G, int TPP, int kphi) {
    __shared__ float s_buf[CC * 18 * 20];   // phase A: tmp[c][16][pn]; then hup[c][18][20]
    __shared__ float s_pw[8 * CC * 9];
    __shared__ int   s_idx[256];
    __shared__ float s_w[HH][4];
    __shared__ int   s_j[HH][4];
    __shared__ unsigned long long s_red[256];
    const int t   = threadIdx.x;
    const int cog = blockIdx.x;   // 0..3
    const int b   = blockIdx.y;   // 0..63
    const int P   = pn * pn;
    const int M   = BB * P;

    // ---- phase 0: cooperative reduce over G key rows (min d, tie -> min v) ----
    {
        int p = t / TPP, sub = t - p * TPP;
        unsigned long long bk = ~0ull;
        if (p < P) {
            int m = b * P + p;
            for (int gg = sub; gg < G; gg += TPP) {
                unsigned long long o = bestk[(size_t)gg * M + m];
                if (o < bk) bk = o;
            }
        }
        s_red[t] = bk;
        __syncthreads();
        for (int s = TPP >> 1; s > 0; s >>= 1) {
            if (sub < s && p < P) {
                unsigned long long o = s_red[t + s];
                if (o < s_red[t]) s_red[t] = o;
            }
            __syncthreads();
        }
        if (t < P) s_idx[t] = (int)(unsigned int)(s_red[t * TPP] & 0xffffffffull);
    }
    if (t < HH) {
        double src = (t + 0.5) * (double)pn / 16.0 - 0.5;
        double fi = floor(src); int i0 = (int)fi; double tt = src - fi;
        #pragma unroll
        for (int k = 0; k < 4; ++k) {
            int j = i0 - 1 + k; j = j < 0 ? 0 : (j > pn - 1 ? pn - 1 : j);
            s_j[t][k] = j;
            s_w[t][k] = (float)cubicw((double)(k - 1) - tt);
        }
    }
    {
        const float* src = pw + ((size_t)(kphi * CC + cog * 8)) * CC * 9;
        for (int i = t; i < 8 * CC * 9; i += 256) s_pw[i] = src[i];
    }
    __syncthreads();

    // ---- phase A: vertical bicubic + gather: tmp[c][h][q] ----
    if (t < HH * pn) {
        int h = t / pn, q = t % pn;
        float acc[CC];
        #pragma unroll
        for (int c = 0; c < CC; ++c) acc[c] = 0.f;
        #pragma unroll
        for (int k = 0; k < 4; ++k) {
            float wv = s_w[h][k];
            int row = s_idx[s_j[h][k] * pn + q];
            const float4* er = (const float4*)(E + (size_t)row * CC);
            #pragma unroll
            for (int c4 = 0; c4 < CC / 4; ++c4) {
                float4 e4 = er[c4];
                acc[c4*4+0] = fmaf(wv, e4.x, acc[c4*4+0]);
                acc[c4*4+1] = fmaf(wv, e4.y, acc[c4*4+1]);
                acc[c4*4+2] = fmaf(wv, e4.z, acc[c4*4+2]);
                acc[c4*4+3] = fmaf(wv, e4.w, acc[c4*4+3]);
            }
        }
        #pragma unroll
        for (int c = 0; c < CC; ++c) s_buf[(c * HH + h) * pn + q] = acc[c];
    }
    __syncthreads();

    // ---- phase B: horizontal bicubic -> padded hup[c][18][20] (data [1..16][1..16]) ----
    {
        int h = t >> 4, w = t & 15;
        float acc[CC];
        #pragma unroll
        for (int c = 0; c < CC; ++c) acc[c] = 0.f;
        #pragma unroll
        for (int k = 0; k < 4; ++k) {
            float wh = s_w[w][k];
            int j = s_j[w][k];
            #pragma unroll
            for (int c = 0; c < CC; ++c)
                acc[c] = fmaf(wh, s_buf[(c * HH + h) * pn + j], acc[c]);
        }
        __syncthreads();   // all tmp reads done before aliased writes
        #pragma unroll
        for (int c = 0; c < CC; ++c) s_buf[(c * 18 + h + 1) * 20 + w + 1] = acc[c];
        if (w == 0) {
            #pragma unroll
            for (int c = 0; c < CC; ++c) s_buf[(c * 18 + h + 1) * 20] = 0.f;
        }
        if (w >= 13) {   // cols 17,18,19
            #pragma unroll
            for (int c = 0; c < CC; ++c) s_buf[(c * 18 + h + 1) * 20 + w + 4] = 0.f;
        }
        if (h == 0) {
            #pragma unroll
            for (int c = 0; c < CC; ++c) {
                s_buf[(c * 18) * 20 + w] = 0.f;
                if (w < 4) s_buf[(c * 18) * 20 + 16 + w] = 0.f;
            }
        }
        if (h == 15) {
            #pragma unroll
            for (int c = 0; c < CC; ++c) {
                s_buf[(c * 18 + 17) * 20 + w] = 0.f;
                if (w < 4) s_buf[(c * 18 + 17) * 20 + 16 + w] = 0.f;
            }
        }
    }
    __syncthreads();

    // ---- conv 3x3 (padded, branch-free) ----
    int col = t >> 5;                 // 0..7
    int co  = cog * 8 + col;
    int s   = t & 31;
    int h   = s >> 1;
    int w0  = (s & 1) * 8;
    float acc[8];
    float bias = pb[kphi * CC + co];
    #pragma unroll
    for (int o = 0; o < 8; ++o) acc[o] = bias;
    for (int ci = 0; ci < CC; ++ci) {
        const float* wrow = &s_pw[(col * CC + ci) * 9];
        #pragma unroll
        for (int kh = 0; kh < 3; ++kh) {
            const float4* xr = (const float4*)&s_buf[(ci * 18 + h + kh) * 20 + w0];
            float4 a0 = xr[0], a1 = xr[1], a2 = xr[2];
            float xf[12] = {a0.x, a0.y, a0.z, a0.w, a1.x, a1.y, a1.z, a1.w,
                            a2.x, a2.y, a2.z, a2.w};
            float k0 = wrow[kh*3+0], k1 = wrow[kh*3+1], k2 = wrow[kh*3+2];
            #pragma unroll
            for (int o = 0; o < 8; ++o)
                acc[o] += xf[o] * k0 + xf[o+1] * k1 + xf[o+2] * k2;
        }
    }
    // ---- epilogue ----
    size_t base = ((size_t)(b * CC + co) * HH + h) * HH + w0;
    float hf[8];
    #pragma unroll
    for (int o = 0; o < 8; ++o) {
        float hv = s_buf[(co * 18 + h + 1) * 20 + w0 + o + 1];
        hf[o] = 0.5f * hv + 0.5f * acc[o];
    }
    float4* fh = (float4*)(f_hat + base);
    float4* fr = (float4*)(f_rest + base);
    float4 v0 = fh[0], v1 = fh[1];
    v0.x += hf[0]; v0.y += hf[1]; v0.z += hf[2]; v0.w += hf[3];
    v1.x += hf[4]; v1.y += hf[5]; v1.z += hf[6]; v1.w += hf[7];
    fh[0] = v0; fh[1] = v1;
    float4 r0 = fr[0], r1 = fr[1];
    r0.x -= hf[0]; r0.y -= hf[1]; r0.z -= hf[2]; r0.w -= hf[3];
    r1.x -= hf[4]; r1.y -= hf[5]; r1.z -= hf[6]; r1.w -= hf[7];
    fr[0] = r0; fr[1] = r1;
}

extern "C" void kernel_launch(void* const* d_in, const int* in_sizes, int n_in,
                              void* d_out, int out_size, void* d_ws, size_t ws_size,
                              hipStream_t stream) {
    const float* f  = (const float*)d_in[0];
    const float* E  = (const float*)d_in[1];
    const float* pw = (const float*)d_in[2];
    const float* pb = (const float*)d_in[3];
    float* out = (float*)d_out;

    float* wsf    = (float*)d_ws;
    float* f_rest = wsf;
    float* e2     = wsf + (size_t)NTOT;
    unsigned long long* bestk = (unsigned long long*)(e2 + VV);  // max 262144 u64
    float* z      = (float*)(bestk + 262144);                    // max 73728 floats

    // numpy _phi_select, bit-exact in IEEE double (ties at si=2,7)
    int phik[10];
    {
        double start = 1.0 / 3.0 / 4.0;
        double stop  = 1.0 - 1.0 / 3.0 / 4.0;
        double step  = (stop - start) / 3.0;
        double ticks[4];
        for (int i = 0; i < 4; ++i) ticks[i] = (double)i * step + start;
        ticks[3] = stop;
        for (int si = 0; si < 10; ++si) {
            double s = (double)si / 9.0;
            int bk = 0; double bd = fabs(ticks[0] - s);
            for (int tq = 1; tq < 4; ++tq) {
                double d2 = fabs(ticks[tq] - s);
                if (d2 < bd) { bd = d2; bk = tq; }
            }
            phik[si] = bk;
        }
    }

    static const int pns[10]  = {1, 2, 3, 4, 5, 6, 8, 10, 13, 16};
    // small scales: blocks = pn^2 * grp, key rows G = 4*grp
    static const int grpS[10] = {256, 128, 64, 32, 32, 16, 0, 0, 0, 0};
    // big scales: blocks = ceil(M/256) * grp, key rows G = grp
    static const int grpB[10] = {0, 0, 0, 0, 0, 0, 64, 32, 16, 16};

    init_k<<<(NTOT + 255) / 256, 256, 0, stream>>>(f, E, f_rest, out, e2);

    for (int si = 0; si < 10; ++si) {
        int pn = pns[si];
        int P = pn * pn;
        int M = BB * P;
        int G, TPP;
        if (pn <= 6) {
            int grp = grpS[si];
            G = grp * 4;
            int gsz = VV / G;
            int n1 = M * CC;
            down_k<<<(n1 + 255) / 256, 256, 0, stream>>>(f_rest, z, pn);
            argsmall_k<<<dim3(P, grp), 256, 0, stream>>>(z, E, e2, bestk, M, gsz);
        } else {
            int grp = grpB[si];
            G = grp;
            int gsz = VV / grp;
            dim3 ag((M + 255) / 256, grp);
            argbig_k<<<ag, 256, 0, stream>>>(f_rest, E, e2, bestk, pn, M, gsz);
        }
        // TPP: largest power of 2 <= 256/P (and >= 1)
        TPP = 1;
        while (TPP * 2 * P <= 256) TPP *= 2;
        fuse_k<<<dim3(4, BB), 256, 0, stream>>>(bestk, E, pw, pb,
                                                out, f_rest, pn, G, TPP, phik[si]);
    }
}